// Round 3
// baseline (439.927 us; speedup 1.0000x reference)
//
#include <hip/hip_runtime.h>
#include <hip/hip_bf16.h>

// Problem: B=32, T=2048, C=1152, O=29.
// z[b,o] = ( (1/64)*dot(W[o,:], s[b,:]) - 2*T*sum(W[o,:]) + T*bias[o] ) / length[b]
// where s[b,c] = sum_t x[b,t,c].
//
// Fully deterministic two-kernel plan (no memset, no atomics):
//   K1: part[p][b][c] = sum over T-slab p of x[b,t,c]   (streams all of x once)
//   K2: per-b block: s[c] = sum_p part[p][b][c] (LDS), then 29 projections.

#define PB 32
#define PT 2048
#define PC 1152
#define PO 29
#define TSPLIT 64
#define SLAB (PT / TSPLIT)   // 32 rows per block
#define C4 (PC / 4)          // 288 float4 per row

typedef float f32x4 __attribute__((ext_vector_type(4)));  // native vector for nontemporal builtin

// grid = (B, TSPLIT), block = 256 (4 waves). Threads cover c4 = tid and
// c4 = 256+tid (tid<32). Writes one contiguous 4.6 KB partial row per block.
__global__ __launch_bounds__(256) void sum_t_kernel(const float* __restrict__ x,
                                                    float* __restrict__ part) {
    const int b   = blockIdx.x;
    const int p   = blockIdx.y;
    const int tid = threadIdx.x;

    const f32x4* x4 = (const f32x4*)(x + (size_t)b * PT * PC)
                    + (size_t)(p * SLAB) * C4;

    f32x4 a0 = (f32x4)(0.f);
    f32x4 a1 = (f32x4)(0.f);

#pragma unroll 8
    for (int t = 0; t < SLAB; ++t) {
        const f32x4* row = x4 + (size_t)t * C4;
        f32x4 v = __builtin_nontemporal_load(&row[tid]);
        a0 += v;
        if (tid < C4 - 256) {
            f32x4 v2 = __builtin_nontemporal_load(&row[256 + tid]);
            a1 += v2;
        }
    }

    f32x4* out4 = (f32x4*)(part + ((size_t)p * PB + b) * PC);
    out4[tid] = a0;
    if (tid < C4 - 256) out4[256 + tid] = a1;
}

// grid = B, block = 256 (4 waves). Stage 1: reduce TSPLIT partials into LDS s[].
// Stage 2: each wave handles o = wave, wave+4, ... ; shuffle-reduce dot & wsum.
__global__ __launch_bounds__(256) void reduce_proj_kernel(const float* __restrict__ part,
                                                          const float* __restrict__ W,
                                                          const float* __restrict__ bias,
                                                          const int* __restrict__ length,
                                                          float* __restrict__ out) {
    __shared__ float s[PC];
    const int b   = blockIdx.x;
    const int tid = threadIdx.x;

    // Stage 1: s[c] = sum_p part[p][b][c], vectorized float4.
    const f32x4* part4 = (const f32x4*)part;
    for (int c4 = tid; c4 < C4; c4 += 256) {
        f32x4 acc = (f32x4)(0.f);
#pragma unroll 8
        for (int p = 0; p < TSPLIT; ++p) {
            acc += part4[((size_t)p * PB + b) * C4 + c4];
        }
        ((f32x4*)s)[c4] = acc;
    }
    __syncthreads();

    const int wave = tid >> 6;
    const int lane = tid & 63;
    const float invlen = 1.0f / (float)length[b];

    for (int o = wave; o < PO; o += 4) {
        const float* Wo = W + o * PC;
        float dot = 0.f, wsum = 0.f;
#pragma unroll
        for (int c = lane; c < PC; c += 64) {
            float w = Wo[c];
            dot  += w * s[c];
            wsum += w;
        }
#pragma unroll
        for (int off = 32; off > 0; off >>= 1) {
            dot  += __shfl_down(dot,  off);
            wsum += __shfl_down(wsum, off);
        }
        if (lane == 0) {
            float z = dot * (1.0f / 64.0f)
                    - 2.0f * (float)PT * wsum
                    + (float)PT * bias[o];
            out[b * PO + o] = z * invlen;
        }
    }
}

extern "C" void kernel_launch(void* const* d_in, const int* in_sizes, int n_in,
                              void* d_out, int out_size, void* d_ws, size_t ws_size,
                              hipStream_t stream) {
    const float* x      = (const float*)d_in[0];
    const int*   length = (const int*)d_in[1];
    const float* W      = (const float*)d_in[2];
    const float* bias   = (const float*)d_in[3];
    float*       out    = (float*)d_out;
    float*       part   = (float*)d_ws;   // [TSPLIT, B, C] partials (9.4 MB)

    dim3 g1(PB, TSPLIT);
    sum_t_kernel<<<g1, 256, 0, stream>>>(x, part);

    reduce_proj_kernel<<<PB, 256, 0, stream>>>(part, W, bias, length, out);
}